// Round 3
// baseline (912.074 us; speedup 1.0000x reference)
//
#include <hip/hip_runtime.h>

#define HDIM 1024
#define TILE 32
#define HALO 20           // 2*PAD
#define MID  52           // TILE + HALO
#define EPSF 1e-8f

// LDS (floats, 13312 = 53248 B -> 3 blocks/CU):
//  hmmT  [0, 7696)    : 52 cols(u) x 74 rows-pitch x float2 (mn,mx), col-major. B..C
//  s_am  [7696, 13312): 52 rows(v) x 54 pitch x float2 (a,mn), row-major.   C..E(fix)
//  hsT   overlay @0   : 32 x 53 double2 (Sa,Sb), col-major(x).              D..E
#define HMMT_PITCH 74
#define AM_OFF 7696
#define AM_PITCH 54
#define HS_PITCH 53

// window-21 min/max scan: 14 outputs o[i] = (min,max) over v[i..i+20], inputs [0..33]
__device__ __forceinline__ void scan14_mm(const float* vm, const float* vx, float2* o) {
    float smn[14], smx[14];
    float amn = vm[20], amx = vx[20];
    #pragma unroll
    for (int j = 19; j >= 14; --j) { amn = fminf(amn, vm[j]); amx = fmaxf(amx, vx[j]); }
    #pragma unroll
    for (int i = 13; i >= 0; --i) {
        amn = fminf(amn, vm[i]); amx = fmaxf(amx, vx[i]);
        smn[i] = amn; smx[i] = amx;
    }
    float pmn = vm[21], pmx = vx[21];
    o[0] = make_float2(smn[0], smx[0]);
    #pragma unroll
    for (int i = 1; i < 14; ++i) {
        o[i] = make_float2(fminf(smn[i], pmn), fmaxf(smx[i], pmx));
        if (i < 13) { pmn = fminf(pmn, vm[21 + i]); pmx = fmaxf(pmx, vx[21 + i]); }
    }
}

__global__ __launch_bounds__(256, 3) void san_kernel(const float* __restrict__ img,
                                                     float* __restrict__ out) {
    __shared__ __align__(16) float smem[13312];
    const int tid = threadIdx.x;
    const int ox0 = blockIdx.x * TILE;
    const int oy0 = blockIdx.y * TILE;
    const float* __restrict__ imc = img + (size_t)blockIdx.z * (HDIM * HDIM);
    float* __restrict__ oc = out + (size_t)blockIdx.z * (HDIM * HDIM);
    const bool xInterior = (blockIdx.x > 0) && (blockIdx.x < gridDim.x - 1);

    // ---- Stage B: horizontal min/max straight from global. 72 rows x 4 groups ----
    for (int task = tid; task < 288; task += 256) {
        int r = task >> 2, u0 = 14 * (task & 3);
        int gy = min(HDIM - 1, max(0, oy0 - HALO + r));
        const float* rowp = imc + gy * HDIM;
        float v[34];
        if (xInterior) {
            const float2* gp = (const float2*)(rowp + (ox0 - HALO + u0));  // even offset
            #pragma unroll
            for (int k = 0; k < 17; ++k) { float2 t = gp[k]; v[2*k] = t.x; v[2*k+1] = t.y; }
        } else {
            #pragma unroll
            for (int j = 0; j < 34; ++j) {
                int gx = ox0 - HALO + u0 + j; gx = min(HDIM - 1, max(0, gx));
                v[j] = rowp[gx];
            }
        }
        float2 o[14];
        scan14_mm(v, v, o);
        #pragma unroll
        for (int i = 0; i < 14; ++i) {
            int u = u0 + i;
            if (u < MID) *(float2*)&smem[2 * (u * HMMT_PITCH + r)] = o[i];  // transposed
        }
    }
    __syncthreads();

    // ---- Stage C: vertical min/max + (a, mn). 52 cols x 4 groups, contiguous b128 reads ----
    if (tid < 208) {
        int u = tid % MID, v0 = 14 * (tid / MID);
        float vm[34], vx[34];
        const float4* p = (const float4*)&smem[2 * (u * HMMT_PITCH + v0)];  // word%4==0
        #pragma unroll
        for (int k = 0; k < 17; ++k) {
            float4 q = p[k];
            vm[2*k] = q.x; vx[2*k] = q.y; vm[2*k+1] = q.z; vx[2*k+1] = q.w;
        }
        float2 o[14];
        scan14_mm(vm, vx, o);
        #pragma unroll
        for (int i = 0; i < 14; ++i) {
            int v = v0 + i;
            if (v < MID) {
                float a = 1.0f / (o[i].y - o[i].x + EPSF);
                *(float2*)&smem[AM_OFF + 2 * (v * AM_PITCH + u)] = make_float2(a, o[i].x);
            }
        }
    }
    __syncthreads();

    // ---- Corner fix-up on tid 255 (idle in D/E): replicate reference f32
    // sequential row-major sums for the 4 degenerate corner pixels ----
    const bool cornerBlk = (blockIdx.x == 0 || blockIdx.x == (HDIM / TILE - 1)) &&
                           (blockIdx.y == 0 || blockIdx.y == (HDIM / TILE - 1));
    float fixVal = 0.0f;
    int fixPy = 0, fixPx = 0;
    if (cornerBlk && tid == 255) {
        fixPy = (blockIdx.y == 0) ? 0 : (TILE - 1);
        fixPx = (blockIdx.x == 0) ? 0 : (TILE - 1);
        float Sa = 0.0f, Sb = 0.0f;
        #pragma unroll 1
        for (int dy = 0; dy < 21; ++dy) {
            #pragma unroll 1
            for (int dx = 0; dx < 21; ++dx) {
                const float* c = &smem[AM_OFF + 2 * ((fixPy + dy) * AM_PITCH + (fixPx + dx))];
                float av = c[0], mnv = c[1];
                float bq = mnv * av;
                asm volatile("" : "+v"(bq));   // keep f32 product rounded (no fma)
                Sa = Sa + av;
                Sb = Sb + bq;
            }
        }
        const float invf = (float)(1.0 / 441.0);
        float avga = Sa * invf;
        float avgb = Sb * invf;
        float pv = imc[(oy0 + fixPy) * HDIM + (ox0 + fixPx)];
        float t = pv * avga;
        asm volatile("" : "+v"(t));
        fixVal = t - avgb;
    }

    // ---- Stage D: horizontal f64 sliding sums of a and a*mn. 52 rows x 2 groups ----
    if (tid < 104) {
        int v = tid >> 1, x0 = 16 * (tid & 1);
        float2 am[36];
        const float4* p = (const float4*)&smem[AM_OFF + 2 * (v * AM_PITCH + x0)];
        #pragma unroll
        for (int k = 0; k < 18; ++k) {
            float4 q = p[k];
            am[2*k]   = make_float2(q.x, q.y);
            am[2*k+1] = make_float2(q.z, q.w);
        }
        double Sa = 0.0, Sb = 0.0;
        #pragma unroll
        for (int j = 0; j < 21; ++j) {
            double ad = (double)am[j].x;
            Sa += ad;
            Sb += ad * (double)am[j].y;
        }
        double2* q = (double2*)smem;   // hsT overlay
        q[x0 * HS_PITCH + v] = make_double2(Sa, Sb);
        #pragma unroll
        for (int t = 1; t < 16; ++t) {
            double ai = (double)am[t + 20].x, ao = (double)am[t - 1].x;
            Sa += ai - ao;
            Sb += ai * (double)am[t + 20].y - ao * (double)am[t - 1].y;
            q[(x0 + t) * HS_PITCH + v] = make_double2(Sa, Sb);
        }
    }
    __syncthreads();

    // ---- Stage E: vertical f64 sliding sums + combine + store. 32 cols x 4 groups ----
    if (tid < 128) {
        int x = tid & 31, y0 = 8 * (tid >> 5);
        const double2* q = (const double2*)smem;
        double2 vv[28];
        #pragma unroll
        for (int j = 0; j < 28; ++j) vv[j] = q[x * HS_PITCH + y0 + j];
        double Sa = 0.0, Sb = 0.0;
        #pragma unroll
        for (int j = 0; j < 21; ++j) { Sa += vv[j].x; Sb += vv[j].y; }
        const double inv_area = 1.0 / 441.0;
        #pragma unroll
        for (int t = 0; t < 8; ++t) {
            if (t > 0) {
                Sa += vv[t + 20].x - vv[t - 1].x;
                Sb += vv[t + 20].y - vv[t - 1].y;
            }
            double va = Sa * inv_area;
            double vb = Sb * inv_area;
            int oy = oy0 + y0 + t, ox = ox0 + x;
            float pix = imc[oy * HDIM + ox];
            oc[oy * HDIM + ox] = (float)((double)pix * va - vb);
        }
    }

    // ---- Corner overwrite (after stage E's write to the same address) ----
    if (cornerBlk) {
        __syncthreads();
        if (tid == 255) {
            oc[(oy0 + fixPy) * HDIM + (ox0 + fixPx)] = fixVal;
        }
    }
}

extern "C" void kernel_launch(void* const* d_in, const int* in_sizes, int n_in,
                              void* d_out, int out_size, void* d_ws, size_t ws_size,
                              hipStream_t stream) {
    const float* img = (const float*)d_in[0];
    float* out = (float*)d_out;
    int nch = in_sizes[0] / (HDIM * HDIM);   // 16*3 = 48
    dim3 grid(HDIM / TILE, HDIM / TILE, nch);
    san_kernel<<<grid, dim3(256), 0, stream>>>(img, out);
}

// Round 4
// 608.667 us; speedup vs baseline: 1.4985x; 1.4985x over previous
//
#include <hip/hip_runtime.h>

#define HDIM 1024
#define TILE 32
#define HALO 20            // 2*PAD
#define MID  52            // TILE + HALO
#define EPSF 1e-8f
#define INVF ((float)(1.0 / 441.0))

// LDS word-offset map (1 word = 4B float), total 13328 words = 53312 B -> 3 blocks/CU.
// Region I  [0, 5616):    s_img 72x74 (A..B)  then  s_ab 52 rows x 54 float2 (C..E)
// Region II [5616,13312): hmmT 52 u-cols x 74 float2 (B..C)  then  hsT 32 x-cols x 53 float2 (D..E)
// +16 words pad for benign tail over-reads of discarded scan lanes.
#define IMG_PITCH 74       // words per staged image row (72 used)
#define REG2 5616
#define HMM_STRIDE 148     // words per hmmT u-column (74 float2: 72 rows + 2 pad)
#define AB_PITCH 108       // words per s_ab row (54 float2)
#define HS_STRIDE 106      // words per hsT x-column (53 float2)
#define SMEM_WORDS 13328

// window-21 min/max scan: o[i] = (min,max) over v[i..i+20], i in [0,14), inputs v[0..33]
__device__ __forceinline__ void scan14_mm(const float* vm, const float* vx, float2* o) {
    float smn[14], smx[14];
    float amn = vm[20], amx = vx[20];
#pragma unroll
    for (int j = 19; j >= 14; --j) { amn = fminf(amn, vm[j]); amx = fmaxf(amx, vx[j]); }
#pragma unroll
    for (int i = 13; i >= 0; --i) {
        amn = fminf(amn, vm[i]); amx = fmaxf(amx, vx[i]);
        smn[i] = amn; smx[i] = amx;
    }
    float pmn = vm[21], pmx = vx[21];
    o[0] = make_float2(smn[0], smx[0]);
#pragma unroll
    for (int i = 1; i < 14; ++i) {
        o[i] = make_float2(fminf(smn[i], pmn), fmaxf(smx[i], pmx));
        if (i < 13) { pmn = fminf(pmn, vm[21 + i]); pmx = fmaxf(pmx, vx[21 + i]); }
    }
}

__global__ __launch_bounds__(256, 3) void san_kernel(const float* __restrict__ img,
                                                     float* __restrict__ out) {
    __shared__ __align__(16) float smem[SMEM_WORDS];
    const int tid = threadIdx.x;
    const int ox0 = blockIdx.x * TILE;
    const int oy0 = blockIdx.y * TILE;
    const float* __restrict__ imc = img + (size_t)blockIdx.z * (HDIM * HDIM);
    float* __restrict__ oc = out + (size_t)blockIdx.z * (HDIM * HDIM);
    const bool xInterior = (blockIdx.x > 0) && (blockIdx.x < gridDim.x - 1);

    // ---- Stage A: stage 72x72 replicate-clamped patch into LDS (coalesced float2) ----
    for (int idx = tid; idx < 72 * 36; idx += 256) {
        int r = idx / 36, c2 = idx - r * 36;
        int gy = min(HDIM - 1, max(0, oy0 - HALO + r));
        float2 t;
        if (xInterior) {
            t = *(const float2*)(imc + gy * HDIM + (ox0 - HALO) + 2 * c2);
        } else {
            int gx0 = min(HDIM - 1, max(0, ox0 - HALO + 2 * c2));
            int gx1 = min(HDIM - 1, max(0, ox0 - HALO + 2 * c2 + 1));
            t = make_float2(imc[gy * HDIM + gx0], imc[gy * HDIM + gx1]);
        }
        *(float2*)&smem[r * IMG_PITCH + 2 * c2] = t;
    }
    __syncthreads();

    // ---- Stage B: horizontal min/max from LDS. 72 rows x 4 groups of 14 = 288 tasks ----
    for (int task = tid; task < 288; task += 256) {
        int r = task >> 2, g = task & 3, u0 = 14 * g;
        const float2* p = (const float2*)&smem[r * IMG_PITCH + u0];
        float v[34];
#pragma unroll
        for (int k = 0; k < 17; ++k) { float2 t = p[k]; v[2 * k] = t.x; v[2 * k + 1] = t.y; }
        float2 o[14];
        scan14_mm(v, v, o);
#pragma unroll
        for (int i = 0; i < 14; ++i) {
            int u = u0 + i;
            if (u < MID) *(float2*)&smem[REG2 + u * HMM_STRIDE + 2 * r] = o[i];  // transposed
        }
    }
    __syncthreads();

    // ---- Stage C: vertical min/max -> (a, b=mn*a). 52 cols x 4 groups = 208 tasks ----
    if (tid < 208) {
        int u = tid % MID, v0 = 14 * (tid / MID);
        const float4* p = (const float4*)&smem[REG2 + u * HMM_STRIDE + 2 * v0];
        float vm[34], vx[34];
#pragma unroll
        for (int k = 0; k < 17; ++k) {
            float4 q = p[k];
            vm[2 * k] = q.x; vx[2 * k] = q.y; vm[2 * k + 1] = q.z; vx[2 * k + 1] = q.w;
        }
        float2 o[14];
        scan14_mm(vm, vx, o);
#pragma unroll
        for (int i = 0; i < 14; ++i) {
            int v = v0 + i;
            if (v < MID) {
                float mn = o[i].x, d = o[i].y - o[i].x;
                float a, b;
                if (d == 0.0f) {      // degenerate corner Q-point: clamp so f32 sliding
                    a = 1.0f;         // sums of neighbors aren't contaminated by 1e8.
                    b = 0.0f;         // Its only true consumer (corner pixel) is fixed up.
                } else {
                    a = 1.0f / (d + EPSF);
                    b = mn * a;
                }
                *(float2*)&smem[v * AB_PITCH + 2 * u] = make_float2(a, b);
            }
        }
    }
    __syncthreads();

    // ---- Stage D (tid<208): horizontal f32 sliding sums. 52 rows x 4 groups of 8.
    //      tid==255 in corner blocks: bit-exact f32 replica of reference for corner pixel. ----
    const bool cornerBlk = (blockIdx.x == 0 || blockIdx.x == gridDim.x - 1) &&
                           (blockIdx.y == 0 || blockIdx.y == gridDim.y - 1);
    float fixVal = 0.0f;
    int fixPy = 0, fixPx = 0;
    if (tid < 208) {
        int v = tid >> 2, g = tid & 3, xb = 8 * g;
        const float4* p = (const float4*)&smem[v * AB_PITCH + 16 * g];
        float2 ab[28];
#pragma unroll
        for (int k = 0; k < 14; ++k) {
            float4 q = p[k];
            ab[2 * k]     = make_float2(q.x, q.y);
            ab[2 * k + 1] = make_float2(q.z, q.w);
        }
        float Sa = 0.0f, Sb = 0.0f;
#pragma unroll
        for (int j = 0; j < 21; ++j) { Sa += ab[j].x; Sb += ab[j].y; }
        *(float2*)&smem[REG2 + xb * HS_STRIDE + 2 * v] = make_float2(Sa, Sb);
#pragma unroll
        for (int t = 1; t < 8; ++t) {
            Sa += ab[t + 20].x - ab[t - 1].x;
            Sb += ab[t + 20].y - ab[t - 1].y;
            *(float2*)&smem[REG2 + (xb + t) * HS_STRIDE + 2 * v] = make_float2(Sa, Sb);
        }
    } else if (cornerBlk && tid == 255) {
        fixPy = (blockIdx.y == 0) ? 0 : (TILE - 1);
        fixPx = (blockIdx.x == 0) ? 0 : (TILE - 1);
        int degY = (blockIdx.y == 0) ? 0 : HALO;   // window-relative pos of degenerate Q
        int degX = (blockIdx.x == 0) ? 0 : HALO;
        float pv = imc[(oy0 + fixPy) * HDIM + (ox0 + fixPx)];
        float aT = 1.0f / EPSF;                    // true a at degenerate point
        float bT = pv * aT;                        // true b (single rounded f32 mul)
        asm volatile("" : "+v"(bT));               // forbid fma contraction into the sum
        float Sa = 0.0f, Sb = 0.0f;
#pragma unroll 1
        for (int dy = 0; dy < 21; ++dy) {
#pragma unroll 1
            for (int dx = 0; dx < 21; ++dx) {
                const float* c = &smem[(fixPy + dy) * AB_PITCH + 2 * (fixPx + dx)];
                float av = c[0], bv = c[1];
                if (dy == degY && dx == degX) { av = aT; bv = bT; }
                Sa = Sa + av;
                Sb = Sb + bv;
            }
        }
        float avga = Sa * INVF;
        float avgb = Sb * INVF;
        float tq = pv * avga;
        asm volatile("" : "+v"(tq));               // mul then sub, like materialized ref
        fixVal = tq - avgb;
    }
    __syncthreads();

    // ---- Stage E: vertical f32 sliding sums + combine + store. 32 cols x 8 groups of 4 = 256 ----
    {
        int x = tid & 31, h = tid >> 5, y0 = 4 * h;
        const float2* p = (const float2*)&smem[REG2 + x * HS_STRIDE + 2 * y0];
        float2 vv[24];
#pragma unroll
        for (int j = 0; j < 24; ++j) vv[j] = p[j];
        float Sa = 0.0f, Sb = 0.0f;
#pragma unroll
        for (int j = 0; j < 21; ++j) { Sa += vv[j].x; Sb += vv[j].y; }
#pragma unroll
        for (int t = 0; t < 4; ++t) {
            if (t > 0) {
                Sa += vv[t + 20].x - vv[t - 1].x;
                Sb += vv[t + 20].y - vv[t - 1].y;
            }
            float avga = Sa * INVF, avgb = Sb * INVF;
            int oy = oy0 + y0 + t, ox = ox0 + x;
            float pix = imc[oy * HDIM + ox];
            oc[oy * HDIM + ox] = pix * avga - avgb;
        }
    }

    // ---- Corner overwrite (after stage E wrote the same address) ----
    if (cornerBlk) {
        __syncthreads();
        if (tid == 255) {
            oc[(oy0 + fixPy) * HDIM + (ox0 + fixPx)] = fixVal;
        }
    }
}

extern "C" void kernel_launch(void* const* d_in, const int* in_sizes, int n_in,
                              void* d_out, int out_size, void* d_ws, size_t ws_size,
                              hipStream_t stream) {
    const float* img = (const float*)d_in[0];
    float* out = (float*)d_out;
    int nch = in_sizes[0] / (HDIM * HDIM);   // 16*3 = 48
    dim3 grid(HDIM / TILE, HDIM / TILE, nch);
    san_kernel<<<grid, dim3(256), 0, stream>>>(img, out);
}

// Round 5
// 608.658 us; speedup vs baseline: 1.4985x; 1.0000x over previous
//
#include <hip/hip_runtime.h>

#define HDIM 1024
#define TILE 32
#define HALO 20            // 2*PAD
#define MID  52            // TILE + HALO
#define EPSF 1e-8f
#define INVF ((float)(1.0 / 441.0))

// LDS word-offset map (1 word = 4B float), total 13328 words = 53312 B -> 3 blocks/CU.
// Region I  [0, 5616):    s_img 72x74 (A..B)  then  s_ab 52 rows x 54 float2 (C..E)
// Region II [5616,13312): hmmT 52 u-cols x 74 float2 (B..C)  then  hsT 32 x-cols x 53 float2 (D..E)
// +16 words pad for benign tail over-reads of discarded scan lanes.
#define IMG_PITCH 74       // words per staged image row (72 used)
#define REG2 5616
#define HMM_STRIDE 148     // words per hmmT u-column (74 float2: 72 rows + 2 pad)
#define AB_PITCH 108       // words per s_ab row (54 float2)
#define HS_STRIDE 106      // words per hsT x-column (53 float2)
#define SMEM_WORDS 13328

// window-21 min/max scan: o[i] = (min,max) over v[i..i+20], i in [0,14), inputs v[0..33]
__device__ __forceinline__ void scan14_mm(const float* vm, const float* vx, float2* o) {
    float smn[14], smx[14];
    float amn = vm[20], amx = vx[20];
#pragma unroll
    for (int j = 19; j >= 14; --j) { amn = fminf(amn, vm[j]); amx = fmaxf(amx, vx[j]); }
#pragma unroll
    for (int i = 13; i >= 0; --i) {
        amn = fminf(amn, vm[i]); amx = fmaxf(amx, vx[i]);
        smn[i] = amn; smx[i] = amx;
    }
    float pmn = vm[21], pmx = vx[21];
    o[0] = make_float2(smn[0], smx[0]);
#pragma unroll
    for (int i = 1; i < 14; ++i) {
        o[i] = make_float2(fminf(smn[i], pmn), fmaxf(smx[i], pmx));
        if (i < 13) { pmn = fminf(pmn, vm[21 + i]); pmx = fmaxf(pmx, vx[21 + i]); }
    }
}

__global__ __launch_bounds__(256, 3) void san_kernel(const float* __restrict__ img,
                                                     float* __restrict__ out) {
    __shared__ __align__(16) float smem[SMEM_WORDS];
    const int tid = threadIdx.x;
    const int ox0 = blockIdx.x * TILE;
    const int oy0 = blockIdx.y * TILE;
    const float* __restrict__ imc = img + (size_t)blockIdx.z * (HDIM * HDIM);
    float* __restrict__ oc = out + (size_t)blockIdx.z * (HDIM * HDIM);
    const bool xInterior = (blockIdx.x > 0) && (blockIdx.x < gridDim.x - 1);

    // ---- Stage A: stage 72x72 replicate-clamped patch into LDS (coalesced float2) ----
    for (int idx = tid; idx < 72 * 36; idx += 256) {
        int r = idx / 36, c2 = idx - r * 36;
        int gy = min(HDIM - 1, max(0, oy0 - HALO + r));
        float2 t;
        if (xInterior) {
            t = *(const float2*)(imc + gy * HDIM + (ox0 - HALO) + 2 * c2);
        } else {
            int gx0 = min(HDIM - 1, max(0, ox0 - HALO + 2 * c2));
            int gx1 = min(HDIM - 1, max(0, ox0 - HALO + 2 * c2 + 1));
            t = make_float2(imc[gy * HDIM + gx0], imc[gy * HDIM + gx1]);
        }
        *(float2*)&smem[r * IMG_PITCH + 2 * c2] = t;
    }
    __syncthreads();

    // ---- Stage B: horizontal min/max from LDS. 72 rows x 4 groups of 14 = 288 tasks ----
    for (int task = tid; task < 288; task += 256) {
        int r = task >> 2, g = task & 3, u0 = 14 * g;
        const float2* p = (const float2*)&smem[r * IMG_PITCH + u0];
        float v[34];
#pragma unroll
        for (int k = 0; k < 17; ++k) { float2 t = p[k]; v[2 * k] = t.x; v[2 * k + 1] = t.y; }
        float2 o[14];
        scan14_mm(v, v, o);
#pragma unroll
        for (int i = 0; i < 14; ++i) {
            int u = u0 + i;
            if (u < MID) *(float2*)&smem[REG2 + u * HMM_STRIDE + 2 * r] = o[i];  // transposed
        }
    }
    __syncthreads();

    // ---- Stage C: vertical min/max -> (a, b=mn*a). 52 cols x 4 groups = 208 tasks ----
    if (tid < 208) {
        int u = tid % MID, v0 = 14 * (tid / MID);
        const float4* p = (const float4*)&smem[REG2 + u * HMM_STRIDE + 2 * v0];
        float vm[34], vx[34];
#pragma unroll
        for (int k = 0; k < 17; ++k) {
            float4 q = p[k];
            vm[2 * k] = q.x; vx[2 * k] = q.y; vm[2 * k + 1] = q.z; vx[2 * k + 1] = q.w;
        }
        float2 o[14];
        scan14_mm(vm, vx, o);
#pragma unroll
        for (int i = 0; i < 14; ++i) {
            int v = v0 + i;
            if (v < MID) {
                float mn = o[i].x, d = o[i].y - o[i].x;
                float a, b;
                if (d == 0.0f) {      // degenerate corner Q-point: clamp so f32 sliding
                    a = 1.0f;         // sums of neighbors aren't contaminated by 1e8.
                    b = 0.0f;         // Its only true consumer (corner pixel) is fixed up.
                } else {
                    a = 1.0f / (d + EPSF);
                    b = mn * a;
                }
                *(float2*)&smem[v * AB_PITCH + 2 * u] = make_float2(a, b);
            }
        }
    }
    __syncthreads();

    // ---- Stage D (tid<208): horizontal f32 sliding sums. 52 rows x 4 groups of 8.
    //      tid==255 in corner blocks: bit-exact f32 replica of reference for corner pixel. ----
    const bool cornerBlk = (blockIdx.x == 0 || blockIdx.x == gridDim.x - 1) &&
                           (blockIdx.y == 0 || blockIdx.y == gridDim.y - 1);
    float fixVal = 0.0f;
    int fixPy = 0, fixPx = 0;
    if (tid < 208) {
        int v = tid >> 2, g = tid & 3, xb = 8 * g;
        const float4* p = (const float4*)&smem[v * AB_PITCH + 16 * g];
        float2 ab[28];
#pragma unroll
        for (int k = 0; k < 14; ++k) {
            float4 q = p[k];
            ab[2 * k]     = make_float2(q.x, q.y);
            ab[2 * k + 1] = make_float2(q.z, q.w);
        }
        float Sa = 0.0f, Sb = 0.0f;
#pragma unroll
        for (int j = 0; j < 21; ++j) { Sa += ab[j].x; Sb += ab[j].y; }
        *(float2*)&smem[REG2 + xb * HS_STRIDE + 2 * v] = make_float2(Sa, Sb);
#pragma unroll
        for (int t = 1; t < 8; ++t) {
            Sa += ab[t + 20].x - ab[t - 1].x;
            Sb += ab[t + 20].y - ab[t - 1].y;
            *(float2*)&smem[REG2 + (xb + t) * HS_STRIDE + 2 * v] = make_float2(Sa, Sb);
        }
    } else if (cornerBlk && tid == 255) {
        fixPy = (blockIdx.y == 0) ? 0 : (TILE - 1);
        fixPx = (blockIdx.x == 0) ? 0 : (TILE - 1);
        int degY = (blockIdx.y == 0) ? 0 : HALO;   // window-relative pos of degenerate Q
        int degX = (blockIdx.x == 0) ? 0 : HALO;
        float pv = imc[(oy0 + fixPy) * HDIM + (ox0 + fixPx)];
        float aT = 1.0f / EPSF;                    // true a at degenerate point
        float bT = pv * aT;                        // true b (single rounded f32 mul)
        asm volatile("" : "+v"(bT));               // forbid fma contraction into the sum
        float Sa = 0.0f, Sb = 0.0f;
#pragma unroll 1
        for (int dy = 0; dy < 21; ++dy) {
#pragma unroll 1
            for (int dx = 0; dx < 21; ++dx) {
                const float* c = &smem[(fixPy + dy) * AB_PITCH + 2 * (fixPx + dx)];
                float av = c[0], bv = c[1];
                if (dy == degY && dx == degX) { av = aT; bv = bT; }
                Sa = Sa + av;
                Sb = Sb + bv;
            }
        }
        float avga = Sa * INVF;
        float avgb = Sb * INVF;
        float tq = pv * avga;
        asm volatile("" : "+v"(tq));               // mul then sub, like materialized ref
        fixVal = tq - avgb;
    }
    __syncthreads();

    // ---- Stage E: vertical f32 sliding sums + combine + store. 32 cols x 8 groups of 4 = 256 ----
    {
        int x = tid & 31, h = tid >> 5, y0 = 4 * h;
        const float2* p = (const float2*)&smem[REG2 + x * HS_STRIDE + 2 * y0];
        float2 vv[24];
#pragma unroll
        for (int j = 0; j < 24; ++j) vv[j] = p[j];
        float Sa = 0.0f, Sb = 0.0f;
#pragma unroll
        for (int j = 0; j < 21; ++j) { Sa += vv[j].x; Sb += vv[j].y; }
#pragma unroll
        for (int t = 0; t < 4; ++t) {
            if (t > 0) {
                Sa += vv[t + 20].x - vv[t - 1].x;
                Sb += vv[t + 20].y - vv[t - 1].y;
            }
            float avga = Sa * INVF, avgb = Sb * INVF;
            int oy = oy0 + y0 + t, ox = ox0 + x;
            float pix = imc[oy * HDIM + ox];
            oc[oy * HDIM + ox] = pix * avga - avgb;
        }
    }

    // ---- Corner overwrite (after stage E wrote the same address) ----
    if (cornerBlk) {
        __syncthreads();
        if (tid == 255) {
            oc[(oy0 + fixPy) * HDIM + (ox0 + fixPx)] = fixVal;
        }
    }
}

extern "C" void kernel_launch(void* const* d_in, const int* in_sizes, int n_in,
                              void* d_out, int out_size, void* d_ws, size_t ws_size,
                              hipStream_t stream) {
    const float* img = (const float*)d_in[0];
    float* out = (float*)d_out;
    int nch = in_sizes[0] / (HDIM * HDIM);   // 16*3 = 48
    dim3 grid(HDIM / TILE, HDIM / TILE, nch);
    san_kernel<<<grid, dim3(256), 0, stream>>>(img, out);
}

// Round 7
// 574.829 us; speedup vs baseline: 1.5867x; 1.0589x over previous
//
#include <hip/hip_runtime.h>

#define HDIM 1024
#define TILE 32
#define HALO 20            // 2*PAD
#define MID  52            // TILE + HALO
#define ABW  1044          // (a,b) grid extent per side
#define ABP2 1056          // (a,b) plane row pitch in float2
#define EPSF 1e-8f
#define INVF ((float)(1.0 / 441.0))

// ======================= split kernels =======================
// K1: img -> (a,b) plane (1044^2, float2 interleaved) ; K2: box-filter + combine.
// Each kernel has only ONE window's halo (20 rows) instead of two (40).

// window-21 min/max scan: o[t] = (min,max) over v[t..t+20], t in [0,8), inputs v[0..27]
__device__ __forceinline__ void scan8_mm(const float* vm, const float* vx, float2* o) {
    float smn[8], smx[8];
    float amn = vm[20], amx = vx[20];
#pragma unroll
    for (int j = 19; j >= 8; --j) { amn = fminf(amn, vm[j]); amx = fmaxf(amx, vx[j]); }
#pragma unroll
    for (int i = 7; i >= 0; --i) {
        amn = fminf(amn, vm[i]); amx = fmaxf(amx, vx[i]);
        smn[i] = amn; smx[i] = amx;
    }
    float pmn = vm[21], pmx = vx[21];
    o[0] = make_float2(smn[0], smx[0]);
#pragma unroll
    for (int i = 1; i < 8; ++i) {
        o[i] = make_float2(fminf(smn[i], pmn), fmaxf(smx[i], pmx));
        if (i < 7) { pmn = fminf(pmn, vm[21 + i]); pmx = fmaxf(pmx, vx[21 + i]); }
    }
}

// K1 LDS: img [52][54] words = 2808 ; hmmT [32 cols][114] words = 3648 ; total 6456 w = 25.8 KB -> 6 blk/CU
#define K1_IMG_PITCH 54
#define K1_HMM_OFF 2808
#define K1_HMM_PITCH 114   // words per hmmT column (52 float2 + pad; 114 mod 32 = 18 -> 2-way max)
#define K1_WORDS 6456

__global__ __launch_bounds__(256, 6) void san_k1(const float* __restrict__ img,
                                                 float2* __restrict__ ab) {
    __shared__ __align__(16) float smem[K1_WORDS];
    const int tid = threadIdx.x;
    const int I0 = blockIdx.x * TILE;
    const int J0 = blockIdx.y * TILE;
    const float* __restrict__ imc = img + (size_t)blockIdx.z * (HDIM * HDIM);
    float2* __restrict__ abc = ab + (size_t)blockIdx.z * ((size_t)ABW * ABP2);
    const bool xInt = (blockIdx.x > 0) && (blockIdx.x < gridDim.x - 1);

    // ---- stage 52x52 replicate-clamped img patch (coalesced float2) ----
    for (int idx = tid; idx < 52 * 26; idx += 256) {
        int r = idx / 26, c2 = idx - r * 26;
        int gy = min(HDIM - 1, max(0, J0 - HALO + r));
        float2 t;
        if (xInt) {
            t = *(const float2*)(imc + gy * HDIM + (I0 - HALO) + 2 * c2);
        } else {
            int gx0 = min(HDIM - 1, max(0, I0 - HALO + 2 * c2));
            int gx1 = min(HDIM - 1, max(0, I0 - HALO + 2 * c2 + 1));
            t = make_float2(imc[gy * HDIM + gx0], imc[gy * HDIM + gx1]);
        }
        *(float2*)&smem[r * K1_IMG_PITCH + 2 * c2] = t;
    }
    __syncthreads();

    // ---- h-scan: 52 rows x 4 groups of 8 = 208 tasks ----
    if (tid < 208) {
        int r = tid >> 2, g = tid & 3;
        const float2* p = (const float2*)&smem[r * K1_IMG_PITCH + 8 * g];
        float v[28];
#pragma unroll
        for (int k = 0; k < 14; ++k) { float2 t = p[k]; v[2 * k] = t.x; v[2 * k + 1] = t.y; }
        float2 o[8];
        scan8_mm(v, v, o);
#pragma unroll
        for (int t = 0; t < 8; ++t) {
            int i = 8 * g + t;
            *(float2*)&smem[K1_HMM_OFF + i * K1_HMM_PITCH + 2 * r] = o[t];  // transposed
        }
    }
    __syncthreads();

    // ---- v-scan + (a,b) + global store: 32 cols x 4 groups of 8 = 128 tasks ----
    if (tid < 128) {
        int i = tid & 31, g = tid >> 5;
        const float2* p = (const float2*)&smem[K1_HMM_OFF + i * K1_HMM_PITCH] + 8 * g;
        float vm[28], vx[28];
#pragma unroll
        for (int k = 0; k < 28; ++k) { float2 t = p[k]; vm[k] = t.x; vx[k] = t.y; }
        float2 o[8];
        scan8_mm(vm, vx, o);
#pragma unroll
        for (int t = 0; t < 8; ++t) {
            int j = 8 * g + t;
            float mn = o[t].x, d = o[t].y - o[t].x;
            float a, b;
            if (d == 0.0f) {      // degenerate corner Q-point: clamp (consumer fixed up in K2)
                a = 1.0f; b = 0.0f;
            } else {
                a = 1.0f / (d + EPSF);
                b = mn * a;
            }
            if ((J0 + j) < ABW && (I0 + i) < ABW)
                abc[(size_t)(J0 + j) * ABP2 + (I0 + i)] = make_float2(a, b);
        }
    }
}

// K2 LDS: ab [52][108] words = 5616 ; hsT [36 cols][106] words = 3816 ; total 9432 w = 37.7 KB -> 4 blk/CU
#define K2_AB_PITCH 108
#define K2_HS_OFF 5616
#define K2_HS_PITCH 106
#define K2_WORDS 9432

__global__ __launch_bounds__(256, 4) void san_k2(const float* __restrict__ img,
                                                 const float2* __restrict__ ab,
                                                 float* __restrict__ out) {
    __shared__ __align__(16) float smem[K2_WORDS];
    const int tid = threadIdx.x;
    const int I0 = blockIdx.x * TILE;
    const int J0 = blockIdx.y * TILE;
    const float* __restrict__ imc = img + (size_t)blockIdx.z * (HDIM * HDIM);
    const float2* __restrict__ abc = ab + (size_t)blockIdx.z * ((size_t)ABW * ABP2);
    float* __restrict__ oc = out + (size_t)blockIdx.z * (HDIM * HDIM);

    // ---- stage ab tile rows J0..J0+51, cols I0..I0+51 (52 float2 = 26 float4 per row) ----
    for (int idx = tid; idx < 52 * 26; idx += 256) {
        int r = idx / 26, c4 = idx - r * 26;
        const float4* gp = (const float4*)(abc + (size_t)(J0 + r) * ABP2 + I0) + c4;
        *(float4*)&smem[r * K2_AB_PITCH + 4 * c4] = *gp;
    }
    __syncthreads();

    // ---- h sliding sums (52 rows x 4 groups of 8 = 208) + corner fixup on tid 255 ----
    const bool cornerBlk = (blockIdx.x == 0 || blockIdx.x == gridDim.x - 1) &&
                           (blockIdx.y == 0 || blockIdx.y == gridDim.y - 1);
    float fixVal = 0.0f;
    int fixPy = 0, fixPx = 0;
    if (tid < 208) {
        int v = tid >> 2, g = tid & 3;
        const float4* p = (const float4*)&smem[v * K2_AB_PITCH + 16 * g];
        float2 abv[28];
#pragma unroll
        for (int k = 0; k < 14; ++k) {
            float4 q = p[k];
            abv[2 * k]     = make_float2(q.x, q.y);
            abv[2 * k + 1] = make_float2(q.z, q.w);
        }
        float Sa = 0.0f, Sb = 0.0f;
#pragma unroll
        for (int j = 0; j < 21; ++j) { Sa += abv[j].x; Sb += abv[j].y; }
        int xp = 9 * g;   // group-padded transposed column index (kills 8*pitch bank hit)
        *(float2*)&smem[K2_HS_OFF + xp * K2_HS_PITCH + 2 * v] = make_float2(Sa, Sb);
#pragma unroll
        for (int t = 1; t < 8; ++t) {
            Sa += abv[t + 20].x - abv[t - 1].x;
            Sb += abv[t + 20].y - abv[t - 1].y;
            *(float2*)&smem[K2_HS_OFF + (xp + t) * K2_HS_PITCH + 2 * v] = make_float2(Sa, Sb);
        }
    } else if (cornerBlk && tid == 255) {
        // bit-exact f32 replica of reference row-major sequential sums for the corner pixel
        fixPy = (blockIdx.y == 0) ? 0 : (TILE - 1);
        fixPx = (blockIdx.x == 0) ? 0 : (TILE - 1);
        int degY = (blockIdx.y == 0) ? 0 : HALO;
        int degX = (blockIdx.x == 0) ? 0 : HALO;
        float pv = imc[(J0 + fixPy) * HDIM + (I0 + fixPx)];
        float aT = 1.0f / EPSF;          // true a at degenerate point
        float bT = pv * aT;              // true b (single rounded f32 mul)
        asm volatile("" : "+v"(bT));     // forbid fma contraction
        float Sa = 0.0f, Sb = 0.0f;
#pragma unroll 1
        for (int dy = 0; dy < 21; ++dy) {
#pragma unroll 1
            for (int dx = 0; dx < 21; ++dx) {
                const float* c = &smem[(fixPy + dy) * K2_AB_PITCH + 2 * (fixPx + dx)];
                float av = c[0], bv = c[1];
                if (dy == degY && dx == degX) { av = aT; bv = bT; }
                Sa = Sa + av;
                Sb = Sb + bv;
            }
        }
        float avga = Sa * INVF;
        float avgb = Sb * INVF;
        float tq = pv * avga;
        asm volatile("" : "+v"(tq));     // mul then sub, like materialized ref
        fixVal = tq - avgb;
    }
    __syncthreads();

    // ---- v sliding sums + combine + store: 32 cols x 8 groups of 4 = 256 tasks ----
    {
        int x = tid & 31, h = tid >> 5, y0 = 4 * h;
        int xp = 9 * (x >> 3) + (x & 7);
        const float2* p = (const float2*)&smem[K2_HS_OFF + xp * K2_HS_PITCH] + y0;
        float2 vv[24];
#pragma unroll
        for (int j = 0; j < 24; ++j) vv[j] = p[j];
        float Sa = 0.0f, Sb = 0.0f;
#pragma unroll
        for (int j = 0; j < 21; ++j) { Sa += vv[j].x; Sb += vv[j].y; }
#pragma unroll
        for (int t = 0; t < 4; ++t) {
            if (t > 0) {
                Sa += vv[t + 20].x - vv[t - 1].x;
                Sb += vv[t + 20].y - vv[t - 1].y;
            }
            float avga = Sa * INVF, avgb = Sb * INVF;
            int oy = J0 + y0 + t, ox = I0 + x;
            float pix = imc[oy * HDIM + ox];
            oc[oy * HDIM + ox] = pix * avga - avgb;
        }
    }

    if (cornerBlk) {
        __syncthreads();
        if (tid == 255) oc[(J0 + fixPy) * HDIM + (I0 + fixPx)] = fixVal;
    }
}

// ======================= fused fallback (R4, proven) =======================
#define IMG_PITCH 74
#define REG2 5616
#define HMM_STRIDE 148
#define AB_PITCH 108
#define HS_STRIDE 106
#define SMEM_WORDS 13328

__device__ __forceinline__ void scan14_mm(const float* vm, const float* vx, float2* o) {
    float smn[14], smx[14];
    float amn = vm[20], amx = vx[20];
#pragma unroll
    for (int j = 19; j >= 14; --j) { amn = fminf(amn, vm[j]); amx = fmaxf(amx, vx[j]); }
#pragma unroll
    for (int i = 13; i >= 0; --i) {
        amn = fminf(amn, vm[i]); amx = fmaxf(amx, vx[i]);
        smn[i] = amn; smx[i] = amx;
    }
    float pmn = vm[21], pmx = vx[21];
    o[0] = make_float2(smn[0], smx[0]);
#pragma unroll
    for (int i = 1; i < 14; ++i) {
        o[i] = make_float2(fminf(smn[i], pmn), fmaxf(smx[i], pmx));
        if (i < 13) { pmn = fminf(pmn, vm[21 + i]); pmx = fmaxf(pmx, vx[21 + i]); }
    }
}

__global__ __launch_bounds__(256, 3) void san_fused(const float* __restrict__ img,
                                                    float* __restrict__ out) {
    __shared__ __align__(16) float smem[SMEM_WORDS];
    const int tid = threadIdx.x;
    const int ox0 = blockIdx.x * TILE;
    const int oy0 = blockIdx.y * TILE;
    const float* __restrict__ imc = img + (size_t)blockIdx.z * (HDIM * HDIM);
    float* __restrict__ oc = out + (size_t)blockIdx.z * (HDIM * HDIM);
    const bool xInterior = (blockIdx.x > 0) && (blockIdx.x < gridDim.x - 1);

    for (int idx = tid; idx < 72 * 36; idx += 256) {
        int r = idx / 36, c2 = idx - r * 36;
        int gy = min(HDIM - 1, max(0, oy0 - HALO + r));
        float2 t;
        if (xInterior) {
            t = *(const float2*)(imc + gy * HDIM + (ox0 - HALO) + 2 * c2);
        } else {
            int gx0 = min(HDIM - 1, max(0, ox0 - HALO + 2 * c2));
            int gx1 = min(HDIM - 1, max(0, ox0 - HALO + 2 * c2 + 1));
            t = make_float2(imc[gy * HDIM + gx0], imc[gy * HDIM + gx1]);
        }
        *(float2*)&smem[r * IMG_PITCH + 2 * c2] = t;
    }
    __syncthreads();

    for (int task = tid; task < 288; task += 256) {
        int r = task >> 2, g = task & 3, u0 = 14 * g;
        const float2* p = (const float2*)&smem[r * IMG_PITCH + u0];
        float v[34];
#pragma unroll
        for (int k = 0; k < 17; ++k) { float2 t = p[k]; v[2 * k] = t.x; v[2 * k + 1] = t.y; }
        float2 o[14];
        scan14_mm(v, v, o);
#pragma unroll
        for (int i = 0; i < 14; ++i) {
            int u = u0 + i;
            if (u < MID) *(float2*)&smem[REG2 + u * HMM_STRIDE + 2 * r] = o[i];
        }
    }
    __syncthreads();

    if (tid < 208) {
        int u = tid % MID, v0 = 14 * (tid / MID);
        const float4* p = (const float4*)&smem[REG2 + u * HMM_STRIDE + 2 * v0];
        float vm[34], vx[34];
#pragma unroll
        for (int k = 0; k < 17; ++k) {
            float4 q = p[k];
            vm[2 * k] = q.x; vx[2 * k] = q.y; vm[2 * k + 1] = q.z; vx[2 * k + 1] = q.w;
        }
        float2 o[14];
        scan14_mm(vm, vx, o);
#pragma unroll
        for (int i = 0; i < 14; ++i) {
            int v = v0 + i;
            if (v < MID) {
                float mn = o[i].x, d = o[i].y - o[i].x;
                float a, b;
                if (d == 0.0f) { a = 1.0f; b = 0.0f; }
                else { a = 1.0f / (d + EPSF); b = mn * a; }
                *(float2*)&smem[v * AB_PITCH + 2 * u] = make_float2(a, b);
            }
        }
    }
    __syncthreads();

    const bool cornerBlk = (blockIdx.x == 0 || blockIdx.x == gridDim.x - 1) &&
                           (blockIdx.y == 0 || blockIdx.y == gridDim.y - 1);
    float fixVal = 0.0f;
    int fixPy = 0, fixPx = 0;
    if (tid < 208) {
        int v = tid >> 2, g = tid & 3, xb = 8 * g;
        const float4* p = (const float4*)&smem[v * AB_PITCH + 16 * g];
        float2 ab[28];
#pragma unroll
        for (int k = 0; k < 14; ++k) {
            float4 q = p[k];
            ab[2 * k]     = make_float2(q.x, q.y);
            ab[2 * k + 1] = make_float2(q.z, q.w);
        }
        float Sa = 0.0f, Sb = 0.0f;
#pragma unroll
        for (int j = 0; j < 21; ++j) { Sa += ab[j].x; Sb += ab[j].y; }
        *(float2*)&smem[REG2 + xb * HS_STRIDE + 2 * v] = make_float2(Sa, Sb);
#pragma unroll
        for (int t = 1; t < 8; ++t) {
            Sa += ab[t + 20].x - ab[t - 1].x;
            Sb += ab[t + 20].y - ab[t - 1].y;
            *(float2*)&smem[REG2 + (xb + t) * HS_STRIDE + 2 * v] = make_float2(Sa, Sb);
        }
    } else if (cornerBlk && tid == 255) {
        fixPy = (blockIdx.y == 0) ? 0 : (TILE - 1);
        fixPx = (blockIdx.x == 0) ? 0 : (TILE - 1);
        int degY = (blockIdx.y == 0) ? 0 : HALO;
        int degX = (blockIdx.x == 0) ? 0 : HALO;
        float pv = imc[(oy0 + fixPy) * HDIM + (ox0 + fixPx)];
        float aT = 1.0f / EPSF;
        float bT = pv * aT;
        asm volatile("" : "+v"(bT));
        float Sa = 0.0f, Sb = 0.0f;
#pragma unroll 1
        for (int dy = 0; dy < 21; ++dy) {
#pragma unroll 1
            for (int dx = 0; dx < 21; ++dx) {
                const float* c = &smem[(fixPy + dy) * AB_PITCH + 2 * (fixPx + dx)];
                float av = c[0], bv = c[1];
                if (dy == degY && dx == degX) { av = aT; bv = bT; }
                Sa = Sa + av;
                Sb = Sb + bv;
            }
        }
        float avga = Sa * INVF;
        float avgb = Sb * INVF;
        float tq = pv * avga;
        asm volatile("" : "+v"(tq));
        fixVal = tq - avgb;
    }
    __syncthreads();

    {
        int x = tid & 31, h = tid >> 5, y0 = 4 * h;
        const float2* p = (const float2*)&smem[REG2 + x * HS_STRIDE + 2 * y0];
        float2 vv[24];
#pragma unroll
        for (int j = 0; j < 24; ++j) vv[j] = p[j];
        float Sa = 0.0f, Sb = 0.0f;
#pragma unroll
        for (int j = 0; j < 21; ++j) { Sa += vv[j].x; Sb += vv[j].y; }
#pragma unroll
        for (int t = 0; t < 4; ++t) {
            if (t > 0) {
                Sa += vv[t + 20].x - vv[t - 1].x;
                Sb += vv[t + 20].y - vv[t - 1].y;
            }
            float avga = Sa * INVF, avgb = Sb * INVF;
            int oy = oy0 + y0 + t, ox = ox0 + x;
            float pix = imc[oy * HDIM + ox];
            oc[oy * HDIM + ox] = pix * avga - avgb;
        }
    }

    if (cornerBlk) {
        __syncthreads();
        if (tid == 255) oc[(oy0 + fixPy) * HDIM + (ox0 + fixPx)] = fixVal;
    }
}

extern "C" void kernel_launch(void* const* d_in, const int* in_sizes, int n_in,
                              void* d_out, int out_size, void* d_ws, size_t ws_size,
                              hipStream_t stream) {
    const float* img = (const float*)d_in[0];
    float* out = (float*)d_out;
    int nch = in_sizes[0] / (HDIM * HDIM);   // 16*3 = 48
    size_t need = (size_t)nch * ABW * ABP2 * sizeof(float2);   // ~404 MiB for 48 ch
    if (ws_size >= need) {
        float2* ab = (float2*)d_ws;
        dim3 g1((ABW + TILE - 1) / TILE, (ABW + TILE - 1) / TILE, nch);   // 33x33
        san_k1<<<g1, dim3(256), 0, stream>>>(img, ab);
        dim3 g2(HDIM / TILE, HDIM / TILE, nch);
        san_k2<<<g2, dim3(256), 0, stream>>>(img, ab, out);
    } else {
        dim3 grid(HDIM / TILE, HDIM / TILE, nch);
        san_fused<<<grid, dim3(256), 0, stream>>>(img, out);
    }
}

// Round 8
// 495.811 us; speedup vs baseline: 1.8396x; 1.1594x over previous
//
#include <hip/hip_runtime.h>

#define HDIM 1024
#define TILE 32
#define HALO 20            // 2*PAD
#define MID  52            // TILE + HALO
#define ABW  1044          // (a,b) grid extent per side
#define ABP2 1056          // (a,b) plane row pitch in float2
#define EPSF 1e-8f
#define INVF ((float)(1.0 / 441.0))

// window-21 min/max scan: o[t] = (min,max) over v[t..t+20], t in [0,8), inputs v[0..27]
__device__ __forceinline__ void scan8_mm(const float* vm, const float* vx, float2* o) {
    float smn[8], smx[8];
    float amn = vm[20], amx = vx[20];
#pragma unroll
    for (int j = 19; j >= 8; --j) { amn = fminf(amn, vm[j]); amx = fmaxf(amx, vx[j]); }
#pragma unroll
    for (int i = 7; i >= 0; --i) {
        amn = fminf(amn, vm[i]); amx = fmaxf(amx, vx[i]);
        smn[i] = amn; smx[i] = amx;
    }
    float pmn = vm[21], pmx = vx[21];
    o[0] = make_float2(smn[0], smx[0]);
#pragma unroll
    for (int i = 1; i < 8; ++i) {
        o[i] = make_float2(fminf(smn[i], pmn), fmaxf(smx[i], pmx));
        if (i < 7) { pmn = fminf(pmn, vm[21 + i]); pmx = fmaxf(pmx, vx[21 + i]); }
    }
}

// ======================= K1: img -> (a,b) plane, 64j x 32i tiles =======================
// LDS: img [84][54] = 4536 w @0 ; hmmT [32 cols][170] = 5440 w @4536 ; total 9976 w = 39.9 KB -> 4 blk/CU
#define K1_IMG_PITCH 54
#define K1_HMM_OFF 4536
#define K1_HMM_PITCH 170
#define K1_WORDS 9984

__global__ __launch_bounds__(256, 4) void san_k1(const float* __restrict__ img,
                                                 float2* __restrict__ ab) {
    __shared__ __align__(16) float smem[K1_WORDS];
    const int tid = threadIdx.x;
    const int I0 = blockIdx.x * 32;
    const int J0 = blockIdx.y * 64;
    const float* __restrict__ imc = img + (size_t)blockIdx.z * (HDIM * HDIM);
    float2* __restrict__ abc = ab + (size_t)blockIdx.z * ((size_t)ABW * ABP2);
    const bool xInt = (blockIdx.x > 0) && (blockIdx.x < gridDim.x - 1);

    // ---- A: stage 84 rows x 52 cols replicate-clamped img (coalesced float2) ----
    for (int idx = tid; idx < 84 * 26; idx += 256) {
        int r = idx / 26, c2 = idx - r * 26;
        int gy = min(HDIM - 1, max(0, J0 - HALO + r));
        float2 t;
        if (xInt) {
            t = *(const float2*)(imc + gy * HDIM + (I0 - HALO) + 2 * c2);
        } else {
            int gx0 = min(HDIM - 1, max(0, I0 - HALO + 2 * c2));
            int gx1 = min(HDIM - 1, max(0, I0 - HALO + 2 * c2 + 1));
            t = make_float2(imc[gy * HDIM + gx0], imc[gy * HDIM + gx1]);
        }
        *(float2*)&smem[r * K1_IMG_PITCH + 2 * c2] = t;
    }
    __syncthreads();

    // ---- B: h-minmax, 84 rows x 4 groups of 8 = 336 tasks; write hmmT (separate region,
    //      so reads/writes don't interfere -> stream task-by-task, no extra barrier) ----
    for (int task = tid; task < 336; task += 256) {
        int r = task >> 2, g = task & 3;
        const float2* p = (const float2*)&smem[r * K1_IMG_PITCH + 8 * g];
        float v[28];
#pragma unroll
        for (int k = 0; k < 14; ++k) { float2 t = p[k]; v[2 * k] = t.x; v[2 * k + 1] = t.y; }
        float2 o[8];
        scan8_mm(v, v, o);
#pragma unroll
        for (int t = 0; t < 8; ++t)
            *(float2*)&smem[K1_HMM_OFF + (8 * g + t) * K1_HMM_PITCH + 2 * r] = o[t];
    }
    __syncthreads();

    // ---- C: v-minmax + (a,b) + global store: 32 cols x 8 groups of 8 = 256 tasks ----
    {
        int i = tid & 31, gj = tid >> 5;
        const float2* p = (const float2*)&smem[K1_HMM_OFF + i * K1_HMM_PITCH + 16 * gj];
        float vm[28], vx[28];
#pragma unroll
        for (int k = 0; k < 28; ++k) { float2 t = p[k]; vm[k] = t.x; vx[k] = t.y; }
        float2 o[8];
        scan8_mm(vm, vx, o);
#pragma unroll
        for (int t = 0; t < 8; ++t) {
            int jj = J0 + 8 * gj + t, ii = I0 + i;
            float mn = o[t].x, d = o[t].y - o[t].x;
            float a, b;
            if (d == 0.0f) {      // degenerate corner Q-point: clamp (consumer fixed up in K2)
                a = 1.0f; b = 0.0f;
            } else {
                a = 1.0f / (d + EPSF);
                b = mn * a;
            }
            if (jj < ABW && ii < ABW)
                abc[(size_t)jj * ABP2 + ii] = make_float2(a, b);
        }
    }
}

// ======================= K2: box-filter + combine, 32x32 tiles =======================
// LDS: single 5620-word region (22.5 KB -> 6+ blk/CU).
//   phase 1-2: ab tile [52][108] ; phase 3-4: hsT [36 cols][106] overlaid at offset 0
//   (h-sums held in registers across the overlay barrier).
#define K2_AB_PITCH 108
#define K2_HS_PITCH 106
#define K2_WORDS 5620

__global__ __launch_bounds__(256, 6) void san_k2(const float* __restrict__ img,
                                                 const float2* __restrict__ ab,
                                                 float* __restrict__ out) {
    __shared__ __align__(16) float smem[K2_WORDS];
    const int tid = threadIdx.x;
    const int I0 = blockIdx.x * TILE;
    const int J0 = blockIdx.y * TILE;
    const float* __restrict__ imc = img + (size_t)blockIdx.z * (HDIM * HDIM);
    const float2* __restrict__ abc = ab + (size_t)blockIdx.z * ((size_t)ABW * ABP2);
    float* __restrict__ oc = out + (size_t)blockIdx.z * (HDIM * HDIM);

    // ---- prefetch this thread's 4 output pixels (used in phase 4) ----
    const int px_x = I0 + (tid & 31);
    const int px_y0 = J0 + 4 * (tid >> 5);
    float pix[4];
#pragma unroll
    for (int t = 0; t < 4; ++t) pix[t] = imc[(px_y0 + t) * HDIM + px_x];

    // ---- phase 1: stage ab tile rows J0..J0+51, 52 float2 (=26 float4) per row ----
    for (int idx = tid; idx < 52 * 26; idx += 256) {
        int r = idx / 26, c4 = idx - r * 26;
        const float4* gp = (const float4*)(abc + (size_t)(J0 + r) * ABP2 + I0) + c4;
        *(float4*)&smem[r * K2_AB_PITCH + 4 * c4] = *gp;
    }
    __syncthreads();

    // ---- phase 2: h sliding sums into REGISTERS (52 rows x 4 groups of 8 = 208 lanes);
    //      corner fixup on lane 255 (reads ab region, must finish before overlay) ----
    const bool cornerBlk = (blockIdx.x == 0 || blockIdx.x == gridDim.x - 1) &&
                           (blockIdx.y == 0 || blockIdx.y == gridDim.y - 1);
    float fixVal = 0.0f;
    int fixPy = 0, fixPx = 0;
    float hsa[8], hsb[8];
    if (tid < 208) {
        int v = tid >> 2, g = tid & 3;
        const float4* p = (const float4*)&smem[v * K2_AB_PITCH + 16 * g];
        float2 abv[28];
#pragma unroll
        for (int k = 0; k < 14; ++k) {
            float4 q = p[k];
            abv[2 * k]     = make_float2(q.x, q.y);
            abv[2 * k + 1] = make_float2(q.z, q.w);
        }
        float Sa = 0.0f, Sb = 0.0f;
#pragma unroll
        for (int j = 0; j < 21; ++j) { Sa += abv[j].x; Sb += abv[j].y; }
        hsa[0] = Sa; hsb[0] = Sb;
#pragma unroll
        for (int t = 1; t < 8; ++t) {
            Sa += abv[t + 20].x - abv[t - 1].x;
            Sb += abv[t + 20].y - abv[t - 1].y;
            hsa[t] = Sa; hsb[t] = Sb;
        }
    } else if (cornerBlk && tid == 255) {
        // bit-exact f32 replica of reference row-major sequential sums for the corner pixel
        fixPy = (blockIdx.y == 0) ? 0 : (TILE - 1);
        fixPx = (blockIdx.x == 0) ? 0 : (TILE - 1);
        int degY = (blockIdx.y == 0) ? 0 : HALO;
        int degX = (blockIdx.x == 0) ? 0 : HALO;
        float pv = imc[(J0 + fixPy) * HDIM + (I0 + fixPx)];
        float aT = 1.0f / EPSF;          // true a at degenerate point
        float bT = pv * aT;              // true b (single rounded f32 mul)
        asm volatile("" : "+v"(bT));     // forbid fma contraction
        float Sa = 0.0f, Sb = 0.0f;
#pragma unroll 1
        for (int dy = 0; dy < 21; ++dy) {
#pragma unroll 1
            for (int dx = 0; dx < 21; ++dx) {
                const float* c = &smem[(fixPy + dy) * K2_AB_PITCH + 2 * (fixPx + dx)];
                float av = c[0], bv = c[1];
                if (dy == degY && dx == degX) { av = aT; bv = bT; }
                Sa = Sa + av;
                Sb = Sb + bv;
            }
        }
        float avga = Sa * INVF;
        float avgb = Sb * INVF;
        float tq = pv * avga;
        asm volatile("" : "+v"(tq));     // mul then sub, like materialized ref
        fixVal = tq - avgb;
    }
    __syncthreads();   // all ab reads done -> safe to overlay hsT

    // ---- phase 3: write transposed h-sums over the dead ab region ----
    if (tid < 208) {
        int v = tid >> 2, g = tid & 3;
        int xp = 9 * g;   // group-padded transposed column index
#pragma unroll
        for (int t = 0; t < 8; ++t)
            *(float2*)&smem[(xp + t) * K2_HS_PITCH + 2 * v] = make_float2(hsa[t], hsb[t]);
    }
    __syncthreads();

    // ---- phase 4: v sliding sums + combine + store: 32 cols x 8 groups of 4 = 256 ----
    {
        int x = tid & 31, h = tid >> 5, y0 = 4 * h;
        int xp = 9 * (x >> 3) + (x & 7);
        const float2* p = (const float2*)&smem[xp * K2_HS_PITCH] + y0;
        float2 vv[24];
#pragma unroll
        for (int j = 0; j < 24; ++j) vv[j] = p[j];
        float Sa = 0.0f, Sb = 0.0f;
#pragma unroll
        for (int j = 0; j < 21; ++j) { Sa += vv[j].x; Sb += vv[j].y; }
#pragma unroll
        for (int t = 0; t < 4; ++t) {
            if (t > 0) {
                Sa += vv[t + 20].x - vv[t - 1].x;
                Sb += vv[t + 20].y - vv[t - 1].y;
            }
            float avga = Sa * INVF, avgb = Sb * INVF;
            oc[(px_y0 + t) * HDIM + px_x] = pix[t] * avga - avgb;
        }
    }

    if (cornerBlk) {
        __syncthreads();
        if (tid == 255) oc[(J0 + fixPy) * HDIM + (I0 + fixPx)] = fixVal;
    }
}

// ======================= fused fallback (R4, proven) =======================
#define IMG_PITCH 74
#define REG2 5616
#define HMM_STRIDE 148
#define AB_PITCH 108
#define HS_STRIDE 106
#define SMEM_WORDS 13328

__device__ __forceinline__ void scan14_mm(const float* vm, const float* vx, float2* o) {
    float smn[14], smx[14];
    float amn = vm[20], amx = vx[20];
#pragma unroll
    for (int j = 19; j >= 14; --j) { amn = fminf(amn, vm[j]); amx = fmaxf(amx, vx[j]); }
#pragma unroll
    for (int i = 13; i >= 0; --i) {
        amn = fminf(amn, vm[i]); amx = fmaxf(amx, vx[i]);
        smn[i] = amn; smx[i] = amx;
    }
    float pmn = vm[21], pmx = vx[21];
    o[0] = make_float2(smn[0], smx[0]);
#pragma unroll
    for (int i = 1; i < 14; ++i) {
        o[i] = make_float2(fminf(smn[i], pmn), fmaxf(smx[i], pmx));
        if (i < 13) { pmn = fminf(pmn, vm[21 + i]); pmx = fmaxf(pmx, vx[21 + i]); }
    }
}

__global__ __launch_bounds__(256, 3) void san_fused(const float* __restrict__ img,
                                                    float* __restrict__ out) {
    __shared__ __align__(16) float smem[SMEM_WORDS];
    const int tid = threadIdx.x;
    const int ox0 = blockIdx.x * TILE;
    const int oy0 = blockIdx.y * TILE;
    const float* __restrict__ imc = img + (size_t)blockIdx.z * (HDIM * HDIM);
    float* __restrict__ oc = out + (size_t)blockIdx.z * (HDIM * HDIM);
    const bool xInterior = (blockIdx.x > 0) && (blockIdx.x < gridDim.x - 1);

    for (int idx = tid; idx < 72 * 36; idx += 256) {
        int r = idx / 36, c2 = idx - r * 36;
        int gy = min(HDIM - 1, max(0, oy0 - HALO + r));
        float2 t;
        if (xInterior) {
            t = *(const float2*)(imc + gy * HDIM + (ox0 - HALO) + 2 * c2);
        } else {
            int gx0 = min(HDIM - 1, max(0, ox0 - HALO + 2 * c2));
            int gx1 = min(HDIM - 1, max(0, ox0 - HALO + 2 * c2 + 1));
            t = make_float2(imc[gy * HDIM + gx0], imc[gy * HDIM + gx1]);
        }
        *(float2*)&smem[r * IMG_PITCH + 2 * c2] = t;
    }
    __syncthreads();

    for (int task = tid; task < 288; task += 256) {
        int r = task >> 2, g = task & 3, u0 = 14 * g;
        const float2* p = (const float2*)&smem[r * IMG_PITCH + u0];
        float v[34];
#pragma unroll
        for (int k = 0; k < 17; ++k) { float2 t = p[k]; v[2 * k] = t.x; v[2 * k + 1] = t.y; }
        float2 o[14];
        scan14_mm(v, v, o);
#pragma unroll
        for (int i = 0; i < 14; ++i) {
            int u = u0 + i;
            if (u < MID) *(float2*)&smem[REG2 + u * HMM_STRIDE + 2 * r] = o[i];
        }
    }
    __syncthreads();

    if (tid < 208) {
        int u = tid % MID, v0 = 14 * (tid / MID);
        const float4* p = (const float4*)&smem[REG2 + u * HMM_STRIDE + 2 * v0];
        float vm[34], vx[34];
#pragma unroll
        for (int k = 0; k < 17; ++k) {
            float4 q = p[k];
            vm[2 * k] = q.x; vx[2 * k] = q.y; vm[2 * k + 1] = q.z; vx[2 * k + 1] = q.w;
        }
        float2 o[14];
        scan14_mm(vm, vx, o);
#pragma unroll
        for (int i = 0; i < 14; ++i) {
            int v = v0 + i;
            if (v < MID) {
                float mn = o[i].x, d = o[i].y - o[i].x;
                float a, b;
                if (d == 0.0f) { a = 1.0f; b = 0.0f; }
                else { a = 1.0f / (d + EPSF); b = mn * a; }
                *(float2*)&smem[v * AB_PITCH + 2 * u] = make_float2(a, b);
            }
        }
    }
    __syncthreads();

    const bool cornerBlk = (blockIdx.x == 0 || blockIdx.x == gridDim.x - 1) &&
                           (blockIdx.y == 0 || blockIdx.y == gridDim.y - 1);
    float fixVal = 0.0f;
    int fixPy = 0, fixPx = 0;
    if (tid < 208) {
        int v = tid >> 2, g = tid & 3, xb = 8 * g;
        const float4* p = (const float4*)&smem[v * AB_PITCH + 16 * g];
        float2 ab[28];
#pragma unroll
        for (int k = 0; k < 14; ++k) {
            float4 q = p[k];
            ab[2 * k]     = make_float2(q.x, q.y);
            ab[2 * k + 1] = make_float2(q.z, q.w);
        }
        float Sa = 0.0f, Sb = 0.0f;
#pragma unroll
        for (int j = 0; j < 21; ++j) { Sa += ab[j].x; Sb += ab[j].y; }
        *(float2*)&smem[REG2 + xb * HS_STRIDE + 2 * v] = make_float2(Sa, Sb);
#pragma unroll
        for (int t = 1; t < 8; ++t) {
            Sa += ab[t + 20].x - ab[t - 1].x;
            Sb += ab[t + 20].y - ab[t - 1].y;
            *(float2*)&smem[REG2 + (xb + t) * HS_STRIDE + 2 * v] = make_float2(Sa, Sb);
        }
    } else if (cornerBlk && tid == 255) {
        fixPy = (blockIdx.y == 0) ? 0 : (TILE - 1);
        fixPx = (blockIdx.x == 0) ? 0 : (TILE - 1);
        int degY = (blockIdx.y == 0) ? 0 : HALO;
        int degX = (blockIdx.x == 0) ? 0 : HALO;
        float pv = imc[(oy0 + fixPy) * HDIM + (ox0 + fixPx)];
        float aT = 1.0f / EPSF;
        float bT = pv * aT;
        asm volatile("" : "+v"(bT));
        float Sa = 0.0f, Sb = 0.0f;
#pragma unroll 1
        for (int dy = 0; dy < 21; ++dy) {
#pragma unroll 1
            for (int dx = 0; dx < 21; ++dx) {
                const float* c = &smem[(fixPy + dy) * AB_PITCH + 2 * (fixPx + dx)];
                float av = c[0], bv = c[1];
                if (dy == degY && dx == degX) { av = aT; bv = bT; }
                Sa = Sa + av;
                Sb = Sb + bv;
            }
        }
        float avga = Sa * INVF;
        float avgb = Sb * INVF;
        float tq = pv * avga;
        asm volatile("" : "+v"(tq));
        fixVal = tq - avgb;
    }
    __syncthreads();

    {
        int x = tid & 31, h = tid >> 5, y0 = 4 * h;
        const float2* p = (const float2*)&smem[REG2 + x * HS_STRIDE + 2 * y0];
        float2 vv[24];
#pragma unroll
        for (int j = 0; j < 24; ++j) vv[j] = p[j];
        float Sa = 0.0f, Sb = 0.0f;
#pragma unroll
        for (int j = 0; j < 21; ++j) { Sa += vv[j].x; Sb += vv[j].y; }
#pragma unroll
        for (int t = 0; t < 4; ++t) {
            if (t > 0) {
                Sa += vv[t + 20].x - vv[t - 1].x;
                Sb += vv[t + 20].y - vv[t - 1].y;
            }
            float avga = Sa * INVF, avgb = Sb * INVF;
            int oy = oy0 + y0 + t, ox = ox0 + x;
            float pix = imc[oy * HDIM + ox];
            oc[oy * HDIM + ox] = pix * avga - avgb;
        }
    }

    if (cornerBlk) {
        __syncthreads();
        if (tid == 255) oc[(oy0 + fixPy) * HDIM + (ox0 + fixPx)] = fixVal;
    }
}

extern "C" void kernel_launch(void* const* d_in, const int* in_sizes, int n_in,
                              void* d_out, int out_size, void* d_ws, size_t ws_size,
                              hipStream_t stream) {
    const float* img = (const float*)d_in[0];
    float* out = (float*)d_out;
    int nch = in_sizes[0] / (HDIM * HDIM);   // 16*3 = 48
    size_t need = (size_t)nch * ABW * ABP2 * sizeof(float2);   // ~404 MiB for 48 ch
    if (ws_size >= need) {
        float2* ab = (float2*)d_ws;
        dim3 g1(33, 17, nch);                 // 32i x 64j tiles over 1044^2
        san_k1<<<g1, dim3(256), 0, stream>>>(img, ab);
        dim3 g2(HDIM / TILE, HDIM / TILE, nch);
        san_k2<<<g2, dim3(256), 0, stream>>>(img, ab, out);
    } else {
        dim3 grid(HDIM / TILE, HDIM / TILE, nch);
        san_fused<<<grid, dim3(256), 0, stream>>>(img, out);
    }
}

// Round 9
// 445.015 us; speedup vs baseline: 2.0495x; 1.1141x over previous
//
#include <hip/hip_runtime.h>

#define HDIM 1024
#define TILE 32
#define HALO 20            // 2*PAD
#define MID  52            // TILE + HALO
#define ABW  1044          // (a,b) grid extent per side
#define ABP2 1056          // (a,b) plane row pitch in float2
#define EPSF 1e-8f
#define INVF ((float)(1.0 / 441.0))

// window-21 min/max scan: o[t] = (min,max) over v[t..t+20], t in [0,8), inputs v[0..27]
__device__ __forceinline__ void scan8_mm(const float* vm, const float* vx, float2* o) {
    float smn[8], smx[8];
    float amn = vm[20], amx = vx[20];
#pragma unroll
    for (int j = 19; j >= 8; --j) { amn = fminf(amn, vm[j]); amx = fmaxf(amx, vx[j]); }
#pragma unroll
    for (int i = 7; i >= 0; --i) {
        amn = fminf(amn, vm[i]); amx = fmaxf(amx, vx[i]);
        smn[i] = amn; smx[i] = amx;
    }
    float pmn = vm[21], pmx = vx[21];
    o[0] = make_float2(smn[0], smx[0]);
#pragma unroll
    for (int i = 1; i < 8; ++i) {
        o[i] = make_float2(fminf(smn[i], pmn), fmaxf(smx[i], pmx));
        if (i < 7) { pmn = fminf(pmn, vm[21 + i]); pmx = fmaxf(pmx, vx[21 + i]); }
    }
}

// ======================= K1: img -> (a,b) plane, 32x32 tiles, LDS overlay =======================
// Single 3776-word region (15.1 KB -> 7-8 blk/CU):
//   phase 1-2: img [52][54] = 2808 w ; phase 3-4: hmmT [32 cols][118] = 3776 w overlaid at 0
//   (h-scan results held in registers across the overlay barrier).
// hmmT row offset roff(j) = 2j + 2*(j>>3)  (pad every 8 rows: breaks the 32-word bank wrap).
#define K1_IMG_PITCH 54
#define K1_HMM_PITCH 118
#define K1_WORDS 3776

__global__ __launch_bounds__(256, 6) void san_k1(const float* __restrict__ img,
                                                 float2* __restrict__ ab) {
    __shared__ __align__(16) float smem[K1_WORDS];
    const int tid = threadIdx.x;
    const int I0 = blockIdx.x * TILE;
    const int J0 = blockIdx.y * TILE;
    const float* __restrict__ imc = img + (size_t)blockIdx.z * (HDIM * HDIM);
    float2* __restrict__ abc = ab + (size_t)blockIdx.z * ((size_t)ABW * ABP2);
    const bool xInt = (blockIdx.x > 0) && (blockIdx.x < gridDim.x - 1);

    // ---- phase 1: stage 52x52 replicate-clamped img patch (coalesced float2) ----
    for (int idx = tid; idx < 52 * 26; idx += 256) {
        int r = idx / 26, c2 = idx - r * 26;
        int gy = min(HDIM - 1, max(0, J0 - HALO + r));
        float2 t;
        if (xInt) {
            t = *(const float2*)(imc + gy * HDIM + (I0 - HALO) + 2 * c2);
        } else {
            int gx0 = min(HDIM - 1, max(0, I0 - HALO + 2 * c2));
            int gx1 = min(HDIM - 1, max(0, I0 - HALO + 2 * c2 + 1));
            t = make_float2(imc[gy * HDIM + gx0], imc[gy * HDIM + gx1]);
        }
        *(float2*)&smem[r * K1_IMG_PITCH + 2 * c2] = t;
    }
    __syncthreads();

    // ---- phase 2: h-minmax into REGISTERS. 52 rows x 4 groups of 8 = 208 lanes ----
    float2 ho[8];
    {
        int r = tid >> 2, g = tid & 3;
        if (tid < 208) {
            const float2* p = (const float2*)&smem[r * K1_IMG_PITCH + 8 * g];
            float v[28];
#pragma unroll
            for (int k = 0; k < 14; ++k) { float2 t = p[k]; v[2 * k] = t.x; v[2 * k + 1] = t.y; }
            scan8_mm(v, v, ho);
        }
    }
    __syncthreads();   // img region dead -> overlay hmmT

    // ---- phase 3: write transposed h-minmax over dead img region ----
    if (tid < 208) {
        int r = tid >> 2, g = tid & 3;
        int rw = 2 * r + 2 * (r >> 3);   // padded row offset
#pragma unroll
        for (int t = 0; t < 8; ++t)
            *(float2*)&smem[(8 * g + t) * K1_HMM_PITCH + rw] = ho[t];
    }
    __syncthreads();

    // ---- phase 4: v-minmax + (a,b) + global store. 32 cols x 4 groups of 8 = 128 lanes ----
    if (tid < 128) {
        int i = tid & 31, gj = tid >> 5;
        const float* base = &smem[i * K1_HMM_PITCH + 18 * gj];
        float vm[28], vx[28];
#pragma unroll
        for (int k = 0; k < 28; ++k) {
            float2 t = *(const float2*)(base + 2 * k + 2 * (k >> 3));
            vm[k] = t.x; vx[k] = t.y;
        }
        float2 o[8];
        scan8_mm(vm, vx, o);
#pragma unroll
        for (int t = 0; t < 8; ++t) {
            int jj = J0 + 8 * gj + t, ii = I0 + i;
            float mn = o[t].x, d = o[t].y - o[t].x;
            float a, b;
            if (d == 0.0f) {      // degenerate corner Q-point: clamp (consumer fixed up in K2)
                a = 1.0f; b = 0.0f;
            } else {
                a = 1.0f / (d + EPSF);
                b = mn * a;
            }
            if (jj < ABW && ii < ABW)
                abc[(size_t)jj * ABP2 + ii] = make_float2(a, b);
        }
    }
}

// ======================= K2: box-filter + combine, 32x32 tiles (proven R8) =======================
#define K2_AB_PITCH 108
#define K2_HS_PITCH 106
#define K2_WORDS 5620

__global__ __launch_bounds__(256, 6) void san_k2(const float* __restrict__ img,
                                                 const float2* __restrict__ ab,
                                                 float* __restrict__ out) {
    __shared__ __align__(16) float smem[K2_WORDS];
    const int tid = threadIdx.x;
    const int I0 = blockIdx.x * TILE;
    const int J0 = blockIdx.y * TILE;
    const float* __restrict__ imc = img + (size_t)blockIdx.z * (HDIM * HDIM);
    const float2* __restrict__ abc = ab + (size_t)blockIdx.z * ((size_t)ABW * ABP2);
    float* __restrict__ oc = out + (size_t)blockIdx.z * (HDIM * HDIM);

    // ---- prefetch this thread's 4 output pixels (used in phase 4) ----
    const int px_x = I0 + (tid & 31);
    const int px_y0 = J0 + 4 * (tid >> 5);
    float pix[4];
#pragma unroll
    for (int t = 0; t < 4; ++t) pix[t] = imc[(px_y0 + t) * HDIM + px_x];

    // ---- phase 1: stage ab tile rows J0..J0+51, 52 float2 (=26 float4) per row ----
    for (int idx = tid; idx < 52 * 26; idx += 256) {
        int r = idx / 26, c4 = idx - r * 26;
        const float4* gp = (const float4*)(abc + (size_t)(J0 + r) * ABP2 + I0) + c4;
        *(float4*)&smem[r * K2_AB_PITCH + 4 * c4] = *gp;
    }
    __syncthreads();

    // ---- phase 2: h sliding sums into REGISTERS (52 rows x 4 groups of 8 = 208 lanes);
    //      corner fixup on lane 255 (reads ab region, must finish before overlay) ----
    const bool cornerBlk = (blockIdx.x == 0 || blockIdx.x == gridDim.x - 1) &&
                           (blockIdx.y == 0 || blockIdx.y == gridDim.y - 1);
    float fixVal = 0.0f;
    int fixPy = 0, fixPx = 0;
    float hsa[8], hsb[8];
    if (tid < 208) {
        int v = tid >> 2, g = tid & 3;
        const float4* p = (const float4*)&smem[v * K2_AB_PITCH + 16 * g];
        float2 abv[28];
#pragma unroll
        for (int k = 0; k < 14; ++k) {
            float4 q = p[k];
            abv[2 * k]     = make_float2(q.x, q.y);
            abv[2 * k + 1] = make_float2(q.z, q.w);
        }
        float Sa = 0.0f, Sb = 0.0f;
#pragma unroll
        for (int j = 0; j < 21; ++j) { Sa += abv[j].x; Sb += abv[j].y; }
        hsa[0] = Sa; hsb[0] = Sb;
#pragma unroll
        for (int t = 1; t < 8; ++t) {
            Sa += abv[t + 20].x - abv[t - 1].x;
            Sb += abv[t + 20].y - abv[t - 1].y;
            hsa[t] = Sa; hsb[t] = Sb;
        }
    } else if (cornerBlk && tid == 255) {
        // bit-exact f32 replica of reference row-major sequential sums for the corner pixel
        fixPy = (blockIdx.y == 0) ? 0 : (TILE - 1);
        fixPx = (blockIdx.x == 0) ? 0 : (TILE - 1);
        int degY = (blockIdx.y == 0) ? 0 : HALO;
        int degX = (blockIdx.x == 0) ? 0 : HALO;
        float pv = imc[(J0 + fixPy) * HDIM + (I0 + fixPx)];
        float aT = 1.0f / EPSF;          // true a at degenerate point
        float bT = pv * aT;              // true b (single rounded f32 mul)
        asm volatile("" : "+v"(bT));     // forbid fma contraction
        float Sa = 0.0f, Sb = 0.0f;
#pragma unroll 1
        for (int dy = 0; dy < 21; ++dy) {
#pragma unroll 1
            for (int dx = 0; dx < 21; ++dx) {
                const float* c = &smem[(fixPy + dy) * K2_AB_PITCH + 2 * (fixPx + dx)];
                float av = c[0], bv = c[1];
                if (dy == degY && dx == degX) { av = aT; bv = bT; }
                Sa = Sa + av;
                Sb = Sb + bv;
            }
        }
        float avga = Sa * INVF;
        float avgb = Sb * INVF;
        float tq = pv * avga;
        asm volatile("" : "+v"(tq));     // mul then sub, like materialized ref
        fixVal = tq - avgb;
    }
    __syncthreads();   // all ab reads done -> safe to overlay hsT

    // ---- phase 3: write transposed h-sums over the dead ab region ----
    if (tid < 208) {
        int v = tid >> 2, g = tid & 3;
        int xp = 9 * g;   // group-padded transposed column index
#pragma unroll
        for (int t = 0; t < 8; ++t)
            *(float2*)&smem[(xp + t) * K2_HS_PITCH + 2 * v] = make_float2(hsa[t], hsb[t]);
    }
    __syncthreads();

    // ---- phase 4: v sliding sums + combine + store: 32 cols x 8 groups of 4 = 256 ----
    {
        int x = tid & 31, h = tid >> 5, y0 = 4 * h;
        int xp = 9 * (x >> 3) + (x & 7);
        const float2* p = (const float2*)&smem[xp * K2_HS_PITCH] + y0;
        float2 vv[24];
#pragma unroll
        for (int j = 0; j < 24; ++j) vv[j] = p[j];
        float Sa = 0.0f, Sb = 0.0f;
#pragma unroll
        for (int j = 0; j < 21; ++j) { Sa += vv[j].x; Sb += vv[j].y; }
#pragma unroll
        for (int t = 0; t < 4; ++t) {
            if (t > 0) {
                Sa += vv[t + 20].x - vv[t - 1].x;
                Sb += vv[t + 20].y - vv[t - 1].y;
            }
            float avga = Sa * INVF, avgb = Sb * INVF;
            oc[(px_y0 + t) * HDIM + px_x] = pix[t] * avga - avgb;
        }
    }

    if (cornerBlk) {
        __syncthreads();
        if (tid == 255) oc[(J0 + fixPy) * HDIM + (I0 + fixPx)] = fixVal;
    }
}

// ======================= fused fallback (R4, proven) =======================
#define IMG_PITCH 74
#define REG2 5616
#define HMM_STRIDE 148
#define AB_PITCH 108
#define HS_STRIDE 106
#define SMEM_WORDS 13328

__device__ __forceinline__ void scan14_mm(const float* vm, const float* vx, float2* o) {
    float smn[14], smx[14];
    float amn = vm[20], amx = vx[20];
#pragma unroll
    for (int j = 19; j >= 14; --j) { amn = fminf(amn, vm[j]); amx = fmaxf(amx, vx[j]); }
#pragma unroll
    for (int i = 13; i >= 0; --i) {
        amn = fminf(amn, vm[i]); amx = fmaxf(amx, vx[i]);
        smn[i] = amn; smx[i] = amx;
    }
    float pmn = vm[21], pmx = vx[21];
    o[0] = make_float2(smn[0], smx[0]);
#pragma unroll
    for (int i = 1; i < 14; ++i) {
        o[i] = make_float2(fminf(smn[i], pmn), fmaxf(smx[i], pmx));
        if (i < 13) { pmn = fminf(pmn, vm[21 + i]); pmx = fmaxf(pmx, vx[21 + i]); }
    }
}

__global__ __launch_bounds__(256, 3) void san_fused(const float* __restrict__ img,
                                                    float* __restrict__ out) {
    __shared__ __align__(16) float smem[SMEM_WORDS];
    const int tid = threadIdx.x;
    const int ox0 = blockIdx.x * TILE;
    const int oy0 = blockIdx.y * TILE;
    const float* __restrict__ imc = img + (size_t)blockIdx.z * (HDIM * HDIM);
    float* __restrict__ oc = out + (size_t)blockIdx.z * (HDIM * HDIM);
    const bool xInterior = (blockIdx.x > 0) && (blockIdx.x < gridDim.x - 1);

    for (int idx = tid; idx < 72 * 36; idx += 256) {
        int r = idx / 36, c2 = idx - r * 36;
        int gy = min(HDIM - 1, max(0, oy0 - HALO + r));
        float2 t;
        if (xInterior) {
            t = *(const float2*)(imc + gy * HDIM + (ox0 - HALO) + 2 * c2);
        } else {
            int gx0 = min(HDIM - 1, max(0, ox0 - HALO + 2 * c2));
            int gx1 = min(HDIM - 1, max(0, ox0 - HALO + 2 * c2 + 1));
            t = make_float2(imc[gy * HDIM + gx0], imc[gy * HDIM + gx1]);
        }
        *(float2*)&smem[r * IMG_PITCH + 2 * c2] = t;
    }
    __syncthreads();

    for (int task = tid; task < 288; task += 256) {
        int r = task >> 2, g = task & 3, u0 = 14 * g;
        const float2* p = (const float2*)&smem[r * IMG_PITCH + u0];
        float v[34];
#pragma unroll
        for (int k = 0; k < 17; ++k) { float2 t = p[k]; v[2 * k] = t.x; v[2 * k + 1] = t.y; }
        float2 o[14];
        scan14_mm(v, v, o);
#pragma unroll
        for (int i = 0; i < 14; ++i) {
            int u = u0 + i;
            if (u < MID) *(float2*)&smem[REG2 + u * HMM_STRIDE + 2 * r] = o[i];
        }
    }
    __syncthreads();

    if (tid < 208) {
        int u = tid % MID, v0 = 14 * (tid / MID);
        const float4* p = (const float4*)&smem[REG2 + u * HMM_STRIDE + 2 * v0];
        float vm[34], vx[34];
#pragma unroll
        for (int k = 0; k < 17; ++k) {
            float4 q = p[k];
            vm[2 * k] = q.x; vx[2 * k] = q.y; vm[2 * k + 1] = q.z; vx[2 * k + 1] = q.w;
        }
        float2 o[14];
        scan14_mm(vm, vx, o);
#pragma unroll
        for (int i = 0; i < 14; ++i) {
            int v = v0 + i;
            if (v < MID) {
                float mn = o[i].x, d = o[i].y - o[i].x;
                float a, b;
                if (d == 0.0f) { a = 1.0f; b = 0.0f; }
                else { a = 1.0f / (d + EPSF); b = mn * a; }
                *(float2*)&smem[v * AB_PITCH + 2 * u] = make_float2(a, b);
            }
        }
    }
    __syncthreads();

    const bool cornerBlk = (blockIdx.x == 0 || blockIdx.x == gridDim.x - 1) &&
                           (blockIdx.y == 0 || blockIdx.y == gridDim.y - 1);
    float fixVal = 0.0f;
    int fixPy = 0, fixPx = 0;
    if (tid < 208) {
        int v = tid >> 2, g = tid & 3, xb = 8 * g;
        const float4* p = (const float4*)&smem[v * AB_PITCH + 16 * g];
        float2 ab[28];
#pragma unroll
        for (int k = 0; k < 14; ++k) {
            float4 q = p[k];
            ab[2 * k]     = make_float2(q.x, q.y);
            ab[2 * k + 1] = make_float2(q.z, q.w);
        }
        float Sa = 0.0f, Sb = 0.0f;
#pragma unroll
        for (int j = 0; j < 21; ++j) { Sa += ab[j].x; Sb += ab[j].y; }
        *(float2*)&smem[REG2 + xb * HS_STRIDE + 2 * v] = make_float2(Sa, Sb);
#pragma unroll
        for (int t = 1; t < 8; ++t) {
            Sa += ab[t + 20].x - ab[t - 1].x;
            Sb += ab[t + 20].y - ab[t - 1].y;
            *(float2*)&smem[REG2 + (xb + t) * HS_STRIDE + 2 * v] = make_float2(Sa, Sb);
        }
    } else if (cornerBlk && tid == 255) {
        fixPy = (blockIdx.y == 0) ? 0 : (TILE - 1);
        fixPx = (blockIdx.x == 0) ? 0 : (TILE - 1);
        int degY = (blockIdx.y == 0) ? 0 : HALO;
        int degX = (blockIdx.x == 0) ? 0 : HALO;
        float pv = imc[(oy0 + fixPy) * HDIM + (ox0 + fixPx)];
        float aT = 1.0f / EPSF;
        float bT = pv * aT;
        asm volatile("" : "+v"(bT));
        float Sa = 0.0f, Sb = 0.0f;
#pragma unroll 1
        for (int dy = 0; dy < 21; ++dy) {
#pragma unroll 1
            for (int dx = 0; dx < 21; ++dx) {
                const float* c = &smem[(fixPy + dy) * AB_PITCH + 2 * (fixPx + dx)];
                float av = c[0], bv = c[1];
                if (dy == degY && dx == degX) { av = aT; bv = bT; }
                Sa = Sa + av;
                Sb = Sb + bv;
            }
        }
        float avga = Sa * INVF;
        float avgb = Sb * INVF;
        float tq = pv * avga;
        asm volatile("" : "+v"(tq));
        fixVal = tq - avgb;
    }
    __syncthreads();

    {
        int x = tid & 31, h = tid >> 5, y0 = 4 * h;
        const float2* p = (const float2*)&smem[REG2 + x * HS_STRIDE + 2 * y0];
        float2 vv[24];
#pragma unroll
        for (int j = 0; j < 24; ++j) vv[j] = p[j];
        float Sa = 0.0f, Sb = 0.0f;
#pragma unroll
        for (int j = 0; j < 21; ++j) { Sa += vv[j].x; Sb += vv[j].y; }
#pragma unroll
        for (int t = 0; t < 4; ++t) {
            if (t > 0) {
                Sa += vv[t + 20].x - vv[t - 1].x;
                Sb += vv[t + 20].y - vv[t - 1].y;
            }
            float avga = Sa * INVF, avgb = Sb * INVF;
            int oy = oy0 + y0 + t, ox = ox0 + x;
            float pix = imc[oy * HDIM + ox];
            oc[oy * HDIM + ox] = pix * avga - avgb;
        }
    }

    if (cornerBlk) {
        __syncthreads();
        if (tid == 255) oc[(oy0 + fixPy) * HDIM + (ox0 + fixPx)] = fixVal;
    }
}

extern "C" void kernel_launch(void* const* d_in, const int* in_sizes, int n_in,
                              void* d_out, int out_size, void* d_ws, size_t ws_size,
                              hipStream_t stream) {
    const float* img = (const float*)d_in[0];
    float* out = (float*)d_out;
    int nch = in_sizes[0] / (HDIM * HDIM);   // 16*3 = 48
    size_t need = (size_t)nch * ABW * ABP2 * sizeof(float2);   // ~404 MiB for 48 ch
    if (ws_size >= need) {
        float2* ab = (float2*)d_ws;
        dim3 g1(33, 33, nch);                 // 32x32 tiles over 1044^2
        san_k1<<<g1, dim3(256), 0, stream>>>(img, ab);
        dim3 g2(HDIM / TILE, HDIM / TILE, nch);
        san_k2<<<g2, dim3(256), 0, stream>>>(img, ab, out);
    } else {
        dim3 grid(HDIM / TILE, HDIM / TILE, nch);
        san_fused<<<grid, dim3(256), 0, stream>>>(img, out);
    }
}